// Round 12
// baseline (709.497 us; speedup 1.0000x reference)
//
#include <hip/hip_runtime.h>
#include <hip/hip_bf16.h>
#include <hip/hip_fp16.h>
#include <stdint.h>

#define BB 2048
#define LL 2048
#define CV 128
#define DD 1024
#define NC 1000
#define EE 6
#define HH 2048

typedef __bf16 bf16_t;
typedef _Float16 f16_t;
typedef __attribute__((ext_vector_type(8))) __bf16 bf16x8;
typedef __attribute__((ext_vector_type(4))) __bf16 bf16x4;
typedef __attribute__((ext_vector_type(8))) _Float16 f16x8;
typedef __attribute__((ext_vector_type(4))) _Float16 f16x4;
typedef __attribute__((ext_vector_type(4))) float f32x4;

// ---- prep: split conv2_w into bf16 hi/lo, LINEAR slices (global-read layout)
// slice t = cb*5 + kk (16KB = 8192 shorts): [split(hi,lo)][co 128][ci 32]
__global__ void k_prep_w2(const float* __restrict__ w2, bf16_t* __restrict__ wsw)
{
    int idx = blockIdx.x * 256 + threadIdx.x;
    if (idx >= 5 * 128 * 128) return;
    int kk = idx % 5;
    int t2 = idx / 5;
    int ci = t2 & 127;
    int co = t2 >> 7;
    float v = w2[idx];
    bf16_t h = (bf16_t)v;
    bf16_t l = (bf16_t)(v - (float)h);
    int t = (ci >> 5) * 5 + kk;
    int j = ci & 31;
    wsw[(size_t)t * 8192 + co * 32 + j]        = h;
    wsw[(size_t)t * 8192 + 4096 + co * 32 + j] = l;
}

// ---- prep: expert / classifier weights fp32 -> f16 --------------------------
__global__ void k_prep_exp(const float* __restrict__ ew1, const float* __restrict__ ew2,
                           const float* __restrict__ cw,  f16_t* __restrict__ ew1h,
                           f16_t* __restrict__ ew2h, f16_t* __restrict__ clsh)
{
    const size_t n1 = (size_t)EE * HH * DD / 4;
    const size_t n2 = n1 + (size_t)EE * DD * HH / 4;
    const size_t n3 = n2 + (size_t)NC * DD / 4;
    size_t i4 = (size_t)blockIdx.x * 256 + threadIdx.x;
    if (i4 >= n3) return;
    const float* src; f16_t* dst; size_t off;
    if (i4 < n1)      { src = ew1; dst = ew1h; off = i4; }
    else if (i4 < n2) { src = ew2; dst = ew2h; off = i4 - n1; }
    else              { src = cw;  dst = clsh; off = i4 - n2; }
    float4 v = reinterpret_cast<const float4*>(src)[off];
    f16x4 r;
    r[0] = (f16_t)v.x; r[1] = (f16_t)v.y; r[2] = (f16_t)v.z; r[3] = (f16_t)v.w;
    reinterpret_cast<f16x4*>(dst)[off] = r;
}

// ---- fused conv1(fp32, LDS-x, 4ci/thread) + conv2(bf16x3 MFMA) + mean -------
// low-VGPR: conv1 wf[20], single A-buf, B n-pair halves -> 3+ waves/SIMD, no spill
__launch_bounds__(256, 3)
__global__ void k_conv(const float* __restrict__ x,  const float* __restrict__ w1,
                       const float* __restrict__ b1, const bf16_t* __restrict__ wsw,
                       const float* __restrict__ b2, float* __restrict__ hbar)
{
    __shared__ __align__(16) float w1s[640];
    __shared__ __align__(16) float b1s[128];
    __shared__ __align__(16) float b2s[128];
    __shared__ __align__(16) float red[4][64];
    __shared__ __align__(16) float xs[528];
    __shared__ __align__(16) short h1s[2][8320];   // [hi/lo][260 rows x 32 ci] swizzled

    const int tid  = threadIdx.x;
    const int b    = blockIdx.x;
    const int lane = tid & 63;
    const int wid  = tid >> 6;                 // 4 waves
    const int l15  = lane & 15, lg = lane >> 4;
    const int wm   = wid >> 1,  wn = wid & 1;  // co-half / t2-half (64 each)
    const int jo   = tid & 7;                  // ci-quad in conv1
    const int rg   = tid >> 3;                 // row group (32 rows/iter)

    for (int i = tid; i < 640; i += 256) w1s[i] = w1[i];
    if (tid < 128) { b1s[tid] = b1[tid]; b2s[tid] = b2[tid]; }

    const float* xrow = x + (size_t)b * LL;
    // per-lane A-fragment offset within a W slice (shorts): co=(wm*64+l15), k-seg lg
    const int aoff = (wm * 64 + l15) * 32 + lg * 8;

    float racc[4][4];
#pragma unroll
    for (int m = 0; m < 4; ++m)
#pragma unroll
        for (int r = 0; r < 4; ++r) racc[m][r] = 0.f;

// one K-step (tap kk): A loaded global->reg at start (single buffer), B from LDS
// in two n-pair halves to cap live registers; split-major MFMA order inside half
#define KSTEP(kk)                                                               \
    do {                                                                        \
        const bf16_t* wp_ = wsw + (size_t)(cb * 5 + (kk)) * 8192 + aoff;        \
        bf16x8 ah[4], al[4];                                                    \
        _Pragma("unroll")                                                       \
        for (int m = 0; m < 4; ++m) {                                           \
            ah[m] = *reinterpret_cast<const bf16x8*>(wp_ + m * 512);            \
            al[m] = *reinterpret_cast<const bf16x8*>(wp_ + 4096 + m * 512);     \
        }                                                                       \
        _Pragma("unroll")                                                       \
        for (int hf = 0; hf < 2; ++hf) {                                        \
            bf16x8 bh[2], bl[2];                                                \
            _Pragma("unroll")                                                   \
            for (int n2 = 0; n2 < 2; ++n2) {                                    \
                int r = 2 * (wn * 64 + (hf * 2 + n2) * 16 + l15) + (kk);        \
                int si = (r * 32 + lg * 8) ^ (((r >> 1) & 7) << 3);             \
                bh[n2] = *reinterpret_cast<const bf16x8*>(&h1s[0][si]);         \
                bl[n2] = *reinterpret_cast<const bf16x8*>(&h1s[1][si]);         \
            }                                                                   \
            _Pragma("unroll")                                                   \
            for (int m = 0; m < 4; ++m)                                         \
                _Pragma("unroll")                                               \
                for (int n2 = 0; n2 < 2; ++n2)                                  \
                    acc[m][hf * 2 + n2] = __builtin_amdgcn_mfma_f32_16x16x32_bf16(ah[m], bh[n2], acc[m][hf * 2 + n2], 0, 0, 0); \
            _Pragma("unroll")                                                   \
            for (int m = 0; m < 4; ++m)                                         \
                _Pragma("unroll")                                               \
                for (int n2 = 0; n2 < 2; ++n2)                                  \
                    acc[m][hf * 2 + n2] = __builtin_amdgcn_mfma_f32_16x16x32_bf16(ah[m], bl[n2], acc[m][hf * 2 + n2], 0, 0, 0); \
            _Pragma("unroll")                                                   \
            for (int m = 0; m < 4; ++m)                                         \
                _Pragma("unroll")                                               \
                for (int n2 = 0; n2 < 2; ++n2)                                  \
                    acc[m][hf * 2 + n2] = __builtin_amdgcn_mfma_f32_16x16x32_bf16(al[m], bh[n2], acc[m][hf * 2 + n2], 0, 0, 0); \
        }                                                                       \
    } while (0)

    for (int c = 0; c < 4; ++c) {
        const int t1base = 256 * c - 2;

        // stage x window [512c-6, 512c+522) (zero-padded); published by next barrier
        {
            const int xoff = 512 * c - 6;
            for (int i = tid; i < 528; i += 256) {
                int xg = xoff + i;
                xs[i] = ((unsigned)xg < 2048u) ? xrow[xg] : 0.f;
            }
        }

        f32x4 acc[4][4];
#pragma unroll
        for (int m = 0; m < 4; ++m)
#pragma unroll
            for (int n = 0; n < 4; ++n)
#pragma unroll
                for (int r = 0; r < 4; ++r) acc[m][n][r] = 0.f;

        for (int cb = 0; cb < 4; ++cb) {
            __syncthreads();   // h1 free (prev cb consumers done) + xs published

            // conv1 for this cb's 32-ci slice: 4 ci per thread, x from LDS
            const int ci0 = cb * 32 + jo * 4;
            float wf[20], br4[4];
#pragma unroll
            for (int q = 0; q < 5; ++q)
                *reinterpret_cast<float4*>(&wf[q * 4]) =
                    *reinterpret_cast<const float4*>(&w1s[ci0 * 5 + q * 4]);
            *reinterpret_cast<float4*>(&br4[0]) = *reinterpret_cast<const float4*>(&b1s[ci0]);

#pragma unroll
            for (int it = 0; it < 9; ++it) {
                int r = rg + it * 32;
                if (it < 8 || r < 260) {
                    bool valid = (unsigned)(t1base + r) < 1024u;
                    float xv[5];
#pragma unroll
                    for (int kk = 0; kk < 5; ++kk) xv[kk] = xs[2 * r + kk];
                    bf16x4 hv, lv;
#pragma unroll
                    for (int u = 0; u < 4; ++u) {
                        float v = br4[u];
#pragma unroll
                        for (int kk = 0; kk < 5; ++kk) v += wf[u * 5 + kk] * xv[kk];
                        v = valid ? fmaxf(v, 0.f) : 0.f;
                        bf16_t h = (bf16_t)v;
                        hv[u] = h;
                        lv[u] = (bf16_t)(v - (float)h);
                    }
                    int si = (r * 32 + jo * 4) ^ (((r >> 1) & 7) << 3);
                    *reinterpret_cast<bf16x4*>(&h1s[0][si]) = hv;
                    *reinterpret_cast<bf16x4*>(&h1s[1][si]) = lv;
                }
            }
            __syncthreads();   // h1 ready

            // 5 K-steps, zero barriers between them
            KSTEP(0);
            KSTEP(1);
            KSTEP(2);
            KSTEP(3);
            KSTEP(4);
        }
        // chunk epilogue: relu(z+b2), accumulate t2 partial sums
#pragma unroll
        for (int m = 0; m < 4; ++m)
#pragma unroll
            for (int r = 0; r < 4; ++r) {
                int co = wm * 64 + m * 16 + lg * 4 + r;
                float bias = b2s[co];
                float s = 0.f;
#pragma unroll
                for (int n = 0; n < 4; ++n) s += fmaxf(acc[m][n][r] + bias, 0.f);
                racc[m][r] += s;
            }
    }
#undef KSTEP

    // reduce 16 t2-columns held across l15 lanes
#pragma unroll
    for (int m = 0; m < 4; ++m)
#pragma unroll
        for (int r = 0; r < 4; ++r) {
            float v = racc[m][r];
            v += __shfl_xor(v, 1);
            v += __shfl_xor(v, 2);
            v += __shfl_xor(v, 4);
            v += __shfl_xor(v, 8);
            racc[m][r] = v;
        }
    __syncthreads();
    if (l15 == 0) {
#pragma unroll
        for (int m = 0; m < 4; ++m)
#pragma unroll
            for (int r = 0; r < 4; ++r)
                red[wid][m * 16 + lg * 4 + r] = racc[m][r];
    }
    __syncthreads();
    if (tid < 128) {
        int wm2 = tid >> 6, loc = tid & 63;
        float s = red[wm2 * 2 + 0][loc] + red[wm2 * 2 + 1][loc];
        hbar[(size_t)b * 128 + tid] = s * (1.f / 512.f);
    }
}

// ---------------- proj: h = hbar @ proj_w^T + proj_b (pure fp32) -------------
__launch_bounds__(256)
__global__ void k_proj(const float* __restrict__ hbar, const float* __restrict__ pw,
                       const float* __restrict__ pb, float* __restrict__ h)
{
    __shared__ float hbs[64 * 128];
    const int tid = threadIdx.x;
    const int b0 = blockIdx.x * 64, d0 = blockIdx.y * 64;
    for (int i = tid * 4; i < 64 * 128; i += 1024)
        *reinterpret_cast<float4*>(&hbs[i]) =
            *reinterpret_cast<const float4*>(&hbar[(size_t)b0 * 128 + i]);
    __syncthreads();
    const int tx = tid & 15, ty = tid >> 4;
    float acc[4][4];
#pragma unroll
    for (int i = 0; i < 4; ++i)
#pragma unroll
        for (int j = 0; j < 4; ++j) acc[i][j] = 0.f;
    const float* pwr[4];
#pragma unroll
    for (int j = 0; j < 4; ++j) pwr[j] = pw + (size_t)(d0 + tx * 4 + j) * 128;
    for (int k = 0; k < 128; k += 4) {
        float4 wv[4], av[4];
#pragma unroll
        for (int j = 0; j < 4; ++j) wv[j] = *reinterpret_cast<const float4*>(pwr[j] + k);
#pragma unroll
        for (int i = 0; i < 4; ++i) av[i] = *reinterpret_cast<const float4*>(&hbs[(ty * 4 + i) * 128 + k]);
#pragma unroll
        for (int i = 0; i < 4; ++i)
#pragma unroll
            for (int j = 0; j < 4; ++j)
                acc[i][j] += av[i].x * wv[j].x + av[i].y * wv[j].y +
                             av[i].z * wv[j].z + av[i].w * wv[j].w;
    }
#pragma unroll
    for (int i = 0; i < 4; ++i) {
        int bb = b0 + ty * 4 + i;
#pragma unroll
        for (int j = 0; j < 4; ++j) {
            int d = d0 + tx * 4 + j;
            h[(size_t)bb * DD + d] = acc[i][j] + pb[d];
        }
    }
}

// ------ router: logits, softmax, top-2 -> combine[b][8], top[b]=int2 ---------
__launch_bounds__(256)
__global__ void k_router(const float* __restrict__ h, const float* __restrict__ rw,
                         const float* __restrict__ rb, float* __restrict__ comb,
                         int2* __restrict__ top)
{
    const int lane = threadIdx.x & 63;
    const int b = blockIdx.x * 4 + (threadIdx.x >> 6);
    float part[6] = {0.f, 0.f, 0.f, 0.f, 0.f, 0.f};
    for (int j = 0; j < 16; ++j) {
        int d = j * 64 + lane;
        float hv = h[(size_t)b * DD + d];
#pragma unroll
        for (int e = 0; e < 6; ++e) part[e] += rw[e * DD + d] * hv;
    }
#pragma unroll
    for (int e = 0; e < 6; ++e) {
        float v = part[e];
        for (int off = 32; off > 0; off >>= 1) v += __shfl_xor(v, off);
        part[e] = v;
    }
    if (lane == 0) {
        float lgt[6];
#pragma unroll
        for (int e = 0; e < 6; ++e) lgt[e] = part[e] + rb[e];
        int i1 = 0;
#pragma unroll
        for (int e = 1; e < 6; ++e) if (lgt[e] > lgt[i1]) i1 = e;
        int i2 = -1;
#pragma unroll
        for (int e = 0; e < 6; ++e)
            if (e != i1 && (i2 < 0 || lgt[e] > lgt[i2])) i2 = e;
        float mx = lgt[i1], s = 0.f, ex[6];
#pragma unroll
        for (int e = 0; e < 6; ++e) { ex[e] = expf(lgt[e] - mx); s += ex[e]; }
        float inv = 1.f / s;
#pragma unroll
        for (int e = 0; e < 6; ++e) comb[b * 8 + e] = 0.f;
        comb[b * 8 + 6] = 0.f; comb[b * 8 + 7] = 0.f;
        comb[b * 8 + i1] = ex[i1] * inv;
        comb[b * 8 + i2] = ex[i2] * inv;
        top[b] = make_int2(i1, i2);
    }
}

// ------ index build: deterministic per-expert compact token lists ------------
__global__ void k_index(const int2* __restrict__ top, int* __restrict__ meta,
                        int* __restrict__ idxg)
{
    __shared__ int wsum[4];
    const int tid = threadIdx.x, lane = tid & 63, wid = tid >> 6;
    int2 tk[8];
#pragma unroll
    for (int j = 0; j < 8; ++j) tk[j] = top[tid * 8 + j];
    int off_run = 0;
    for (int e = 0; e < 6; ++e) {
        int m[8], c = 0;
#pragma unroll
        for (int j = 0; j < 8; ++j) { m[j] = (tk[j].x == e || tk[j].y == e) ? 1 : 0; c += m[j]; }
        int v = c;
        for (int d = 1; d < 64; d <<= 1) { int u = __shfl_up(v, d); if (lane >= d) v += u; }
        if (lane == 63) wsum[wid] = v;
        __syncthreads();
        int wbase = 0;
#pragma unroll
        for (int w = 0; w < 4; ++w) if (w < wid) wbase += wsum[w];
        int total = wsum[0] + wsum[1] + wsum[2] + wsum[3];
        int p = off_run + wbase + (v - c);
#pragma unroll
        for (int j = 0; j < 8; ++j) if (m[j]) idxg[p++] = tid * 8 + j;
        if (tid == 0) { meta[e] = total; meta[8 + e] = off_run; }
        off_run += total;
        __syncthreads();
    }
    if (tid == 0) meta[14] = off_run;
}

// ---------------- sparse MoE GEMMs + classifier ------------------------------
__device__ inline f16x8 cvt8(const float4 a, const float4 b)
{
    f16x8 r;
    r[0] = (f16_t)a.x; r[1] = (f16_t)a.y; r[2] = (f16_t)a.z; r[3] = (f16_t)a.w;
    r[4] = (f16_t)b.x; r[5] = (f16_t)b.y; r[6] = (f16_t)b.z; r[7] = (f16_t)b.w;
    return r;
}

// EPI 1: A = gather(h) f32, B = ew1, out = relu -> hidg (f16, compact rows)
// EPI 2: A = hidg f16,      B = ew2, out = scatter w*(c+b) -> eog f16 slots
// EPI 3: A = eog slot-sum,  B = cls_w, out = final logits f32
template<int EPI, int NFRAG>
__launch_bounds__(256, 3)
__global__ void k_moe(const float* __restrict__ hsrc, const f16_t* __restrict__ hidg,
                      const f16_t* __restrict__ eog, const float* __restrict__ Bp,
                      const f16_t* __restrict__ Bh, const float* __restrict__ bias,
                      f16_t* __restrict__ outH, f16_t* __restrict__ eogW,
                      float* __restrict__ outF, const float* __restrict__ comb,
                      const int2* __restrict__ top, const int* __restrict__ meta,
                      const int* __restrict__ idxg, int N, int K, int NCLIP)
{
    constexpr int BN = NFRAG * 32;
    __shared__ f16_t As[128 * 72];
    __shared__ f16_t Bs[BN * 72];
    const int tid = threadIdx.x;
    const int e  = blockIdx.z;
    const int m0 = blockIdx.x * 128, n0 = blockIdx.y * BN;
    int cnt = 1 << 30, off = 0;
    if (EPI != 3) {
        cnt = meta[e]; off = meta[8 + e];
        if (m0 >= cnt) return;
    }
    const int lane = tid & 63, wid = tid >> 6;
    const int l15 = lane & 15, lg = lane >> 4;
    const int wm = wid >> 1, wn = wid & 1;

    f32x4 acc[4][NFRAG];
#pragma unroll
    for (int i = 0; i < 4; ++i)
#pragma unroll
        for (int j = 0; j < NFRAG; ++j)
#pragma unroll
            for (int r = 0; r < 4; ++r) acc[i][j][r] = 0.f;

    for (int k0 = 0; k0 < K; k0 += 64) {
        __syncthreads();
        {
            const int row = tid >> 1, c0 = (tid & 1) * 32;
            f16x8* d = reinterpret_cast<f16x8*>(As + row * 72 + c0);
            if (EPI == 1) {
                int lr = m0 + row;
                int token = (lr < cnt) ? idxg[off + lr] : 0;
                const float4* s = reinterpret_cast<const float4*>(hsrc + (size_t)token * K + k0 + c0);
#pragma unroll
                for (int j = 0; j < 4; ++j) d[j] = cvt8(s[2 * j], s[2 * j + 1]);
            } else if (EPI == 2) {
                const uint4* s = reinterpret_cast<const uint4*>(hidg + (size_t)(off + m0 + row) * K + k0 + c0);
#pragma unroll
                for (int j = 0; j < 4; ++j) reinterpret_cast<uint4*>(d)[j] = s[j];
            } else {
                int r = m0 + row;
                const f16x8* s0 = reinterpret_cast<const f16x8*>(eog + ((size_t)r * 2) * K + k0 + c0);
                const f16x8* s1 = reinterpret_cast<const f16x8*>(eog + ((size_t)r * 2 + 1) * K + k0 + c0);
#pragma unroll
                for (int j = 0; j < 4; ++j) d[j] = s0[j] + s1[j];
            }
        }
        {
            constexpr int PERTHR = BN * 64 / 256;
            constexpr int TPR = 64 / PERTHR;
            const int row = tid / TPR, c0 = (tid % TPR) * PERTHR;
            const bool ok = (n0 + row) < NCLIP;
            f16x8* d = reinterpret_cast<f16x8*>(Bs + row * 72 + c0);
            if (Bh) {
                const uint4* s = reinterpret_cast<const uint4*>(
                    Bh + (size_t)e * N * K + (size_t)(n0 + row) * K + k0 + c0);
#pragma unroll
                for (int j = 0; j < PERTHR / 8; ++j) {
                    uint4 v = ok ? s[j] : make_uint4(0, 0, 0, 0);
                    reinterpret_cast<uint4*>(d)[j] = v;
                }
            } else {
                const float4* s = reinterpret_cast<const float4*>(
                    Bp + (size_t)e * N * K + (size_t)(n0 + row) * K + k0 + c0);
#pragma unroll
                for (int j = 0; j < PERTHR / 8; ++j) {
                    float4 a = ok ? s[2 * j]     : make_float4(0.f, 0.f, 0.f, 0.f);
                    float4 b = ok ? s[2 * j + 1] : make_float4(0.f, 0.f, 0.f, 0.f);
                    d[j] = cvt8(a, b);
                }
            }
        }
        __syncthreads();
#pragma unroll
        for (int kk = 0; kk < 64; kk += 32) {
            f16x8 af[4], bq[NFRAG];
#pragma unroll
            for (int i = 0; i < 4; ++i)
                af[i] = *reinterpret_cast<const f16x8*>(As + (wm * 64 + i * 16 + l15) * 72 + kk + lg * 8);
#pragma unroll
            for (int j = 0; j < NFRAG; ++j)
                bq[j] = *reinterpret_cast<const f16x8*>(Bs + (wn * (BN / 2) + j * 16 + l15) * 72 + kk + lg * 8);
#pragma unroll
            for (int i = 0; i < 4; ++i)
#pragma unroll
                for (int j = 0; j < NFRAG; ++j)
                    acc[i][j] = __builtin_amdgcn_mfma_f32_16x16x32_f16(af[i], bq[j], acc[i][j], 0, 0, 0);
        }
    }
#pragma unroll
    for (int i = 0; i < 4; ++i) {
#pragma unroll
        for (int j = 0; j < NFRAG; ++j) {
#pragma unroll
            for (int r = 0; r < 4; ++r) {
                int lr  = m0 + wm * 64 + i * 16 + lg * 4 + r;
                int col = n0 + wn * (BN / 2) + j * 16 + l15;
                float c = acc[i][j][r];
                if (EPI == 1) {
                    if (lr < cnt)
                        outH[(size_t)(off + lr) * N + col] = (f16_t)fmaxf(c + bias[(size_t)e * N + col], 0.f);
                } else if (EPI == 2) {
                    if (lr < cnt) {
                        int token = idxg[off + lr];
                        int slot = (top[token].x == e) ? 0 : 1;
                        float w = comb[token * 8 + e];
                        eogW[((size_t)token * 2 + slot) * N + col] = (f16_t)(w * (c + bias[(size_t)e * N + col]));
                    }
                } else {
                    if (col < NCLIP)
                        outF[(size_t)lr * NCLIP + col] = c + bias[col];
                }
            }
        }
    }
}

// -----------------------------------------------------------------------------
extern "C" void kernel_launch(void* const* d_in, const int* in_sizes, int n_in,
                              void* d_out, int out_size, void* d_ws, size_t ws_size,
                              hipStream_t stream)
{
    const float* x   = (const float*)d_in[0];
    const float* w1  = (const float*)d_in[1];
    const float* b1  = (const float*)d_in[2];
    const float* w2  = (const float*)d_in[3];
    const float* b2  = (const float*)d_in[4];
    const float* pw  = (const float*)d_in[5];
    const float* pb  = (const float*)d_in[6];
    const float* rw  = (const float*)d_in[7];
    const float* rb  = (const float*)d_in[8];
    const float* ew1 = (const float*)d_in[9];
    const float* eb1 = (const float*)d_in[10];
    const float* ew2 = (const float*)d_in[11];
    const float* eb2 = (const float*)d_in[12];
    const float* cw  = (const float*)d_in[13];
    const float* cb  = (const float*)d_in[14];
    float* out = (float*)d_out;

    char* ws = (char*)d_ws;
    bf16_t* wsw  = (bf16_t*)(ws + 0);            //  320 KB
    float*  hbar = (float*)(ws + 327680);        //    1 MB
    float*  h    = (float*)(ws + 1376256);       //    8 MB (f32) — later reused as eog
    f16_t*  eog  = (f16_t*)(ws + 1376256);       //    8 MB f16 [token][slot][D] (aliases h)
    float*  comb = (float*)(ws + 9764864);       //   64 KB
    int2*   top  = (int2*)(ws + 9830400);        //   16 KB
    int*    meta = (int*)(ws + 9846784);         //   64 B
    int*    idxg = (int*)(ws + 9847040);         //   16 KB
    f16_t*  hidg = (f16_t*)(ws + 9863424);       // 16.5 MB -> ends 27164928
    f16_t*  ew1h = (f16_t*)(ws + 27164928);      //   24 MB
    f16_t*  ew2h = (f16_t*)(ws + 52330752);      //   24 MB
    f16_t*  clsh = (f16_t*)(ws + 77496576);      //    2 MB -> 79593728

    const bool f16w = ws_size >= 79593728ull;

    k_prep_w2<<<320, 256, 0, stream>>>(w2, wsw);
    if (f16w)
        k_prep_exp<<<25576, 256, 0, stream>>>(ew1, ew2, cw, ew1h, ew2h, clsh);
    k_conv<<<2048, 256, 0, stream>>>(x, w1, b1, wsw, b2, hbar);
    k_proj<<<dim3(32, 16), 256, 0, stream>>>(hbar, pw, pb, h);
    k_router<<<512, 256, 0, stream>>>(h, rw, rb, comb, top);
    k_index<<<1, 256, 0, stream>>>(top, meta, idxg);
    k_moe<1, 4><<<dim3(16, 16, 6), 256, 0, stream>>>(
        h, nullptr, nullptr, ew1, f16w ? ew1h : nullptr, eb1,
        hidg, nullptr, nullptr, comb, top, meta, idxg, HH, DD, HH);
    k_moe<2, 4><<<dim3(16, 8, 6), 256, 0, stream>>>(
        nullptr, hidg, nullptr, ew2, f16w ? ew2h : nullptr, eb2,
        nullptr, eog, nullptr, comb, top, meta, idxg, DD, HH, DD);
    k_moe<3, 2><<<dim3(16, 16, 1), 256, 0, stream>>>(
        nullptr, nullptr, eog, cw, f16w ? clsh : nullptr, cb,
        nullptr, nullptr, out, comb, top, meta, idxg, DD, DD, NC);
}

// Round 13
// 708.454 us; speedup vs baseline: 1.0015x; 1.0015x over previous
//
#include <hip/hip_runtime.h>
#include <hip/hip_bf16.h>
#include <hip/hip_fp16.h>
#include <stdint.h>

#define BB 2048
#define LL 2048
#define CV 128
#define DD 1024
#define NC 1000
#define EE 6
#define HH 2048

typedef __bf16 bf16_t;
typedef _Float16 f16_t;
typedef __attribute__((ext_vector_type(8))) __bf16 bf16x8;
typedef __attribute__((ext_vector_type(4))) __bf16 bf16x4;
typedef __attribute__((ext_vector_type(8))) _Float16 f16x8;
typedef __attribute__((ext_vector_type(4))) _Float16 f16x4;
typedef __attribute__((ext_vector_type(4))) float f32x4;

// ---- prep: split conv2_w into bf16 hi/lo, LINEAR slices (global-read layout)
// slice t = cb*5 + kk (16KB = 8192 shorts): [split(hi,lo)][co 128][ci 32]
__global__ void k_prep_w2(const float* __restrict__ w2, bf16_t* __restrict__ wsw)
{
    int idx = blockIdx.x * 256 + threadIdx.x;
    if (idx >= 5 * 128 * 128) return;
    int kk = idx % 5;
    int t2 = idx / 5;
    int ci = t2 & 127;
    int co = t2 >> 7;
    float v = w2[idx];
    bf16_t h = (bf16_t)v;
    bf16_t l = (bf16_t)(v - (float)h);
    int t = (ci >> 5) * 5 + kk;
    int j = ci & 31;
    wsw[(size_t)t * 8192 + co * 32 + j]        = h;
    wsw[(size_t)t * 8192 + 4096 + co * 32 + j] = l;
}

// ---- prep: expert / classifier weights fp32 -> f16 --------------------------
__global__ void k_prep_exp(const float* __restrict__ ew1, const float* __restrict__ ew2,
                           const float* __restrict__ cw,  f16_t* __restrict__ ew1h,
                           f16_t* __restrict__ ew2h, f16_t* __restrict__ clsh)
{
    const size_t n1 = (size_t)EE * HH * DD / 4;
    const size_t n2 = n1 + (size_t)EE * DD * HH / 4;
    const size_t n3 = n2 + (size_t)NC * DD / 4;
    size_t i4 = (size_t)blockIdx.x * 256 + threadIdx.x;
    if (i4 >= n3) return;
    const float* src; f16_t* dst; size_t off;
    if (i4 < n1)      { src = ew1; dst = ew1h; off = i4; }
    else if (i4 < n2) { src = ew2; dst = ew2h; off = i4 - n1; }
    else              { src = cw;  dst = clsh; off = i4 - n2; }
    float4 v = reinterpret_cast<const float4*>(src)[off];
    f16x4 r;
    r[0] = (f16_t)v.x; r[1] = (f16_t)v.y; r[2] = (f16_t)v.z; r[3] = (f16_t)v.w;
    reinterpret_cast<f16x4*>(dst)[off] = r;
}

// ---- fused conv1(fp32, LDS-x, 4ci/thread, ROLLED loop) + conv2(bf16x3) + mean
// rolled conv1 keeps transient pressure low -> no spill at (256,3)
__launch_bounds__(256, 3)
__global__ void k_conv(const float* __restrict__ x,  const float* __restrict__ w1,
                       const float* __restrict__ b1, const bf16_t* __restrict__ wsw,
                       const float* __restrict__ b2, float* __restrict__ hbar)
{
    __shared__ __align__(16) float w1s[640];
    __shared__ __align__(16) float b1s[128];
    __shared__ __align__(16) float b2s[128];
    __shared__ __align__(16) float red[4][64];
    __shared__ __align__(16) float xs[528];
    __shared__ __align__(16) short h1s[2][8320];   // [hi/lo][260 rows x 32 ci] swizzled

    const int tid  = threadIdx.x;
    const int b    = blockIdx.x;
    const int lane = tid & 63;
    const int wid  = tid >> 6;                 // 4 waves
    const int l15  = lane & 15, lg = lane >> 4;
    const int wm   = wid >> 1,  wn = wid & 1;  // co-half / t2-half (64 each)
    const int jo   = tid & 7;                  // ci-quad in conv1
    const int rg   = tid >> 3;                 // row group (32 rows/iter)

    for (int i = tid; i < 640; i += 256) w1s[i] = w1[i];
    if (tid < 128) { b1s[tid] = b1[tid]; b2s[tid] = b2[tid]; }

    const float* xrow = x + (size_t)b * LL;
    // per-lane A-fragment offset within a W slice (shorts): co=(wm*64+l15), k-seg lg
    const int aoff = (wm * 64 + l15) * 32 + lg * 8;

    float racc[4][4];
#pragma unroll
    for (int m = 0; m < 4; ++m)
#pragma unroll
        for (int r = 0; r < 4; ++r) racc[m][r] = 0.f;

// one K-step (tap kk): A loaded global->reg at start (single buffer), B from LDS
// in two n-pair halves to cap live registers; split-major MFMA order inside half
#define KSTEP(kk)                                                               \
    do {                                                                        \
        const bf16_t* wp_ = wsw + (size_t)(cb * 5 + (kk)) * 8192 + aoff;        \
        bf16x8 ah[4], al[4];                                                    \
        _Pragma("unroll")                                                       \
        for (int m = 0; m < 4; ++m) {                                           \
            ah[m] = *reinterpret_cast<const bf16x8*>(wp_ + m * 512);            \
            al[m] = *reinterpret_cast<const bf16x8*>(wp_ + 4096 + m * 512);     \
        }                                                                       \
        _Pragma("unroll")                                                       \
        for (int hf = 0; hf < 2; ++hf) {                                        \
            bf16x8 bh[2], bl[2];                                                \
            _Pragma("unroll")                                                   \
            for (int n2 = 0; n2 < 2; ++n2) {                                    \
                int r = 2 * (wn * 64 + (hf * 2 + n2) * 16 + l15) + (kk);        \
                int si = (r * 32 + lg * 8) ^ (((r >> 1) & 7) << 3);             \
                bh[n2] = *reinterpret_cast<const bf16x8*>(&h1s[0][si]);         \
                bl[n2] = *reinterpret_cast<const bf16x8*>(&h1s[1][si]);         \
            }                                                                   \
            _Pragma("unroll")                                                   \
            for (int m = 0; m < 4; ++m)                                         \
                _Pragma("unroll")                                               \
                for (int n2 = 0; n2 < 2; ++n2)                                  \
                    acc[m][hf * 2 + n2] = __builtin_amdgcn_mfma_f32_16x16x32_bf16(ah[m], bh[n2], acc[m][hf * 2 + n2], 0, 0, 0); \
            _Pragma("unroll")                                                   \
            for (int m = 0; m < 4; ++m)                                         \
                _Pragma("unroll")                                               \
                for (int n2 = 0; n2 < 2; ++n2)                                  \
                    acc[m][hf * 2 + n2] = __builtin_amdgcn_mfma_f32_16x16x32_bf16(ah[m], bl[n2], acc[m][hf * 2 + n2], 0, 0, 0); \
            _Pragma("unroll")                                                   \
            for (int m = 0; m < 4; ++m)                                         \
                _Pragma("unroll")                                               \
                for (int n2 = 0; n2 < 2; ++n2)                                  \
                    acc[m][hf * 2 + n2] = __builtin_amdgcn_mfma_f32_16x16x32_bf16(al[m], bh[n2], acc[m][hf * 2 + n2], 0, 0, 0); \
        }                                                                       \
    } while (0)

    for (int c = 0; c < 4; ++c) {
        const int t1base = 256 * c - 2;

        // stage x window [512c-6, 512c+522) (zero-padded); published by next barrier
        {
            const int xoff = 512 * c - 6;
            for (int i = tid; i < 528; i += 256) {
                int xg = xoff + i;
                xs[i] = ((unsigned)xg < 2048u) ? xrow[xg] : 0.f;
            }
        }

        f32x4 acc[4][4];
#pragma unroll
        for (int m = 0; m < 4; ++m)
#pragma unroll
            for (int n = 0; n < 4; ++n)
#pragma unroll
                for (int r = 0; r < 4; ++r) acc[m][n][r] = 0.f;

        for (int cb = 0; cb < 4; ++cb) {
            __syncthreads();   // h1 free (prev cb consumers done) + xs published

            // conv1 for this cb's 32-ci slice: 4 ci per thread, x from LDS
            // ROLLED loop: keeps transient register pressure to one iteration
            const int ci0 = cb * 32 + jo * 4;
            float wf[20], br4[4];
#pragma unroll
            for (int q = 0; q < 5; ++q)
                *reinterpret_cast<float4*>(&wf[q * 4]) =
                    *reinterpret_cast<const float4*>(&w1s[ci0 * 5 + q * 4]);
            *reinterpret_cast<float4*>(&br4[0]) = *reinterpret_cast<const float4*>(&b1s[ci0]);

#pragma unroll 1
            for (int it = 0; it < 9; ++it) {
                int r = rg + it * 32;
                if (r < 260) {
                    bool valid = (unsigned)(t1base + r) < 1024u;
                    float xv[5];
#pragma unroll
                    for (int kk = 0; kk < 5; ++kk) xv[kk] = xs[2 * r + kk];
                    bf16x4 hv, lv;
#pragma unroll
                    for (int u = 0; u < 4; ++u) {
                        float v = br4[u];
#pragma unroll
                        for (int kk = 0; kk < 5; ++kk) v += wf[u * 5 + kk] * xv[kk];
                        v = valid ? fmaxf(v, 0.f) : 0.f;
                        bf16_t h = (bf16_t)v;
                        hv[u] = h;
                        lv[u] = (bf16_t)(v - (float)h);
                    }
                    int si = (r * 32 + jo * 4) ^ (((r >> 1) & 7) << 3);
                    *reinterpret_cast<bf16x4*>(&h1s[0][si]) = hv;
                    *reinterpret_cast<bf16x4*>(&h1s[1][si]) = lv;
                }
            }
            __syncthreads();   // h1 ready

            // 5 K-steps, zero barriers between them
            KSTEP(0);
            KSTEP(1);
            KSTEP(2);
            KSTEP(3);
            KSTEP(4);
        }
        // chunk epilogue: relu(z+b2), accumulate t2 partial sums
#pragma unroll
        for (int m = 0; m < 4; ++m)
#pragma unroll
            for (int r = 0; r < 4; ++r) {
                int co = wm * 64 + m * 16 + lg * 4 + r;
                float bias = b2s[co];
                float s = 0.f;
#pragma unroll
                for (int n = 0; n < 4; ++n) s += fmaxf(acc[m][n][r] + bias, 0.f);
                racc[m][r] += s;
            }
    }
#undef KSTEP

    // reduce 16 t2-columns held across l15 lanes
#pragma unroll
    for (int m = 0; m < 4; ++m)
#pragma unroll
        for (int r = 0; r < 4; ++r) {
            float v = racc[m][r];
            v += __shfl_xor(v, 1);
            v += __shfl_xor(v, 2);
            v += __shfl_xor(v, 4);
            v += __shfl_xor(v, 8);
            racc[m][r] = v;
        }
    __syncthreads();
    if (l15 == 0) {
#pragma unroll
        for (int m = 0; m < 4; ++m)
#pragma unroll
            for (int r = 0; r < 4; ++r)
                red[wid][m * 16 + lg * 4 + r] = racc[m][r];
    }
    __syncthreads();
    if (tid < 128) {
        int wm2 = tid >> 6, loc = tid & 63;
        float s = red[wm2 * 2 + 0][loc] + red[wm2 * 2 + 1][loc];
        hbar[(size_t)b * 128 + tid] = s * (1.f / 512.f);
    }
}

// ---------------- proj: h = hbar @ proj_w^T + proj_b (pure fp32) -------------
__launch_bounds__(256)
__global__ void k_proj(const float* __restrict__ hbar, const float* __restrict__ pw,
                       const float* __restrict__ pb, float* __restrict__ h)
{
    __shared__ float hbs[64 * 128];
    const int tid = threadIdx.x;
    const int b0 = blockIdx.x * 64, d0 = blockIdx.y * 64;
    for (int i = tid * 4; i < 64 * 128; i += 1024)
        *reinterpret_cast<float4*>(&hbs[i]) =
            *reinterpret_cast<const float4*>(&hbar[(size_t)b0 * 128 + i]);
    __syncthreads();
    const int tx = tid & 15, ty = tid >> 4;
    float acc[4][4];
#pragma unroll
    for (int i = 0; i < 4; ++i)
#pragma unroll
        for (int j = 0; j < 4; ++j) acc[i][j] = 0.f;
    const float* pwr[4];
#pragma unroll
    for (int j = 0; j < 4; ++j) pwr[j] = pw + (size_t)(d0 + tx * 4 + j) * 128;
    for (int k = 0; k < 128; k += 4) {
        float4 wv[4], av[4];
#pragma unroll
        for (int j = 0; j < 4; ++j) wv[j] = *reinterpret_cast<const float4*>(pwr[j] + k);
#pragma unroll
        for (int i = 0; i < 4; ++i) av[i] = *reinterpret_cast<const float4*>(&hbs[(ty * 4 + i) * 128 + k]);
#pragma unroll
        for (int i = 0; i < 4; ++i)
#pragma unroll
            for (int j = 0; j < 4; ++j)
                acc[i][j] += av[i].x * wv[j].x + av[i].y * wv[j].y +
                             av[i].z * wv[j].z + av[i].w * wv[j].w;
    }
#pragma unroll
    for (int i = 0; i < 4; ++i) {
        int bb = b0 + ty * 4 + i;
#pragma unroll
        for (int j = 0; j < 4; ++j) {
            int d = d0 + tx * 4 + j;
            h[(size_t)bb * DD + d] = acc[i][j] + pb[d];
        }
    }
}

// ------ router: logits, softmax, top-2 -> combine[b][8], top[b]=int2 ---------
__launch_bounds__(256)
__global__ void k_router(const float* __restrict__ h, const float* __restrict__ rw,
                         const float* __restrict__ rb, float* __restrict__ comb,
                         int2* __restrict__ top)
{
    const int lane = threadIdx.x & 63;
    const int b = blockIdx.x * 4 + (threadIdx.x >> 6);
    float part[6] = {0.f, 0.f, 0.f, 0.f, 0.f, 0.f};
    for (int j = 0; j < 16; ++j) {
        int d = j * 64 + lane;
        float hv = h[(size_t)b * DD + d];
#pragma unroll
        for (int e = 0; e < 6; ++e) part[e] += rw[e * DD + d] * hv;
    }
#pragma unroll
    for (int e = 0; e < 6; ++e) {
        float v = part[e];
        for (int off = 32; off > 0; off >>= 1) v += __shfl_xor(v, off);
        part[e] = v;
    }
    if (lane == 0) {
        float lgt[6];
#pragma unroll
        for (int e = 0; e < 6; ++e) lgt[e] = part[e] + rb[e];
        int i1 = 0;
#pragma unroll
        for (int e = 1; e < 6; ++e) if (lgt[e] > lgt[i1]) i1 = e;
        int i2 = -1;
#pragma unroll
        for (int e = 0; e < 6; ++e)
            if (e != i1 && (i2 < 0 || lgt[e] > lgt[i2])) i2 = e;
        float mx = lgt[i1], s = 0.f, ex[6];
#pragma unroll
        for (int e = 0; e < 6; ++e) { ex[e] = expf(lgt[e] - mx); s += ex[e]; }
        float inv = 1.f / s;
#pragma unroll
        for (int e = 0; e < 6; ++e) comb[b * 8 + e] = 0.f;
        comb[b * 8 + 6] = 0.f; comb[b * 8 + 7] = 0.f;
        comb[b * 8 + i1] = ex[i1] * inv;
        comb[b * 8 + i2] = ex[i2] * inv;
        top[b] = make_int2(i1, i2);
    }
}

// ------ index build: deterministic per-expert compact token lists ------------
__global__ void k_index(const int2* __restrict__ top, int* __restrict__ meta,
                        int* __restrict__ idxg)
{
    __shared__ int wsum[4];
    const int tid = threadIdx.x, lane = tid & 63, wid = tid >> 6;
    int2 tk[8];
#pragma unroll
    for (int j = 0; j < 8; ++j) tk[j] = top[tid * 8 + j];
    int off_run = 0;
    for (int e = 0; e < 6; ++e) {
        int m[8], c = 0;
#pragma unroll
        for (int j = 0; j < 8; ++j) { m[j] = (tk[j].x == e || tk[j].y == e) ? 1 : 0; c += m[j]; }
        int v = c;
        for (int d = 1; d < 64; d <<= 1) { int u = __shfl_up(v, d); if (lane >= d) v += u; }
        if (lane == 63) wsum[wid] = v;
        __syncthreads();
        int wbase = 0;
#pragma unroll
        for (int w = 0; w < 4; ++w) if (w < wid) wbase += wsum[w];
        int total = wsum[0] + wsum[1] + wsum[2] + wsum[3];
        int p = off_run + wbase + (v - c);
#pragma unroll
        for (int j = 0; j < 8; ++j) if (m[j]) idxg[p++] = tid * 8 + j;
        if (tid == 0) { meta[e] = total; meta[8 + e] = off_run; }
        off_run += total;
        __syncthreads();
    }
    if (tid == 0) meta[14] = off_run;
}

// ---------------- sparse MoE GEMMs + classifier ------------------------------
__device__ inline f16x8 cvt8(const float4 a, const float4 b)
{
    f16x8 r;
    r[0] = (f16_t)a.x; r[1] = (f16_t)a.y; r[2] = (f16_t)a.z; r[3] = (f16_t)a.w;
    r[4] = (f16_t)b.x; r[5] = (f16_t)b.y; r[6] = (f16_t)b.z; r[7] = (f16_t)b.w;
    return r;
}

// EPI 1: A = gather(h) f32, B = ew1, out = relu -> hidg (f16, compact rows)
// EPI 2: A = hidg f16,      B = ew2, out = scatter w*(c+b) -> eog f16 slots
// EPI 3: A = eog slot-sum,  B = cls_w, out = final logits f32
template<int EPI, int NFRAG>
__launch_bounds__(256, 3)
__global__ void k_moe(const float* __restrict__ hsrc, const f16_t* __restrict__ hidg,
                      const f16_t* __restrict__ eog, const float* __restrict__ Bp,
                      const f16_t* __restrict__ Bh, const float* __restrict__ bias,
                      f16_t* __restrict__ outH, f16_t* __restrict__ eogW,
                      float* __restrict__ outF, const float* __restrict__ comb,
                      const int2* __restrict__ top, const int* __restrict__ meta,
                      const int* __restrict__ idxg, int N, int K, int NCLIP)
{
    constexpr int BN = NFRAG * 32;
    __shared__ f16_t As[128 * 72];
    __shared__ f16_t Bs[BN * 72];
    const int tid = threadIdx.x;
    const int e  = blockIdx.z;
    const int m0 = blockIdx.x * 128, n0 = blockIdx.y * BN;
    int cnt = 1 << 30, off = 0;
    if (EPI != 3) {
        cnt = meta[e]; off = meta[8 + e];
        if (m0 >= cnt) return;
    }
    const int lane = tid & 63, wid = tid >> 6;
    const int l15 = lane & 15, lg = lane >> 4;
    const int wm = wid >> 1, wn = wid & 1;

    f32x4 acc[4][NFRAG];
#pragma unroll
    for (int i = 0; i < 4; ++i)
#pragma unroll
        for (int j = 0; j < NFRAG; ++j)
#pragma unroll
            for (int r = 0; r < 4; ++r) acc[i][j][r] = 0.f;

    for (int k0 = 0; k0 < K; k0 += 64) {
        __syncthreads();
        {
            const int row = tid >> 1, c0 = (tid & 1) * 32;
            f16x8* d = reinterpret_cast<f16x8*>(As + row * 72 + c0);
            if (EPI == 1) {
                int lr = m0 + row;
                int token = (lr < cnt) ? idxg[off + lr] : 0;
                const float4* s = reinterpret_cast<const float4*>(hsrc + (size_t)token * K + k0 + c0);
#pragma unroll
                for (int j = 0; j < 4; ++j) d[j] = cvt8(s[2 * j], s[2 * j + 1]);
            } else if (EPI == 2) {
                const uint4* s = reinterpret_cast<const uint4*>(hidg + (size_t)(off + m0 + row) * K + k0 + c0);
#pragma unroll
                for (int j = 0; j < 4; ++j) reinterpret_cast<uint4*>(d)[j] = s[j];
            } else {
                int r = m0 + row;
                const f16x8* s0 = reinterpret_cast<const f16x8*>(eog + ((size_t)r * 2) * K + k0 + c0);
                const f16x8* s1 = reinterpret_cast<const f16x8*>(eog + ((size_t)r * 2 + 1) * K + k0 + c0);
#pragma unroll
                for (int j = 0; j < 4; ++j) d[j] = s0[j] + s1[j];
            }
        }
        {
            constexpr int PERTHR = BN * 64 / 256;
            constexpr int TPR = 64 / PERTHR;
            const int row = tid / TPR, c0 = (tid % TPR) * PERTHR;
            const bool ok = (n0 + row) < NCLIP;
            f16x8* d = reinterpret_cast<f16x8*>(Bs + row * 72 + c0);
            if (Bh) {
                const uint4* s = reinterpret_cast<const uint4*>(
                    Bh + (size_t)e * N * K + (size_t)(n0 + row) * K + k0 + c0);
#pragma unroll
                for (int j = 0; j < PERTHR / 8; ++j) {
                    uint4 v = ok ? s[j] : make_uint4(0, 0, 0, 0);
                    reinterpret_cast<uint4*>(d)[j] = v;
                }
            } else {
                const float4* s = reinterpret_cast<const float4*>(
                    Bp + (size_t)e * N * K + (size_t)(n0 + row) * K + k0 + c0);
#pragma unroll
                for (int j = 0; j < PERTHR / 8; ++j) {
                    float4 a = ok ? s[2 * j]     : make_float4(0.f, 0.f, 0.f, 0.f);
                    float4 b = ok ? s[2 * j + 1] : make_float4(0.f, 0.f, 0.f, 0.f);
                    d[j] = cvt8(a, b);
                }
            }
        }
        __syncthreads();
#pragma unroll
        for (int kk = 0; kk < 64; kk += 32) {
            f16x8 af[4], bq[NFRAG];
#pragma unroll
            for (int i = 0; i < 4; ++i)
                af[i] = *reinterpret_cast<const f16x8*>(As + (wm * 64 + i * 16 + l15) * 72 + kk + lg * 8);
#pragma unroll
            for (int j = 0; j < NFRAG; ++j)
                bq[j] = *reinterpret_cast<const f16x8*>(Bs + (wn * (BN / 2) + j * 16 + l15) * 72 + kk + lg * 8);
#pragma unroll
            for (int i = 0; i < 4; ++i)
#pragma unroll
                for (int j = 0; j < NFRAG; ++j)
                    acc[i][j] = __builtin_amdgcn_mfma_f32_16x16x32_f16(af[i], bq[j], acc[i][j], 0, 0, 0);
        }
    }
#pragma unroll
    for (int i = 0; i < 4; ++i) {
#pragma unroll
        for (int j = 0; j < NFRAG; ++j) {
#pragma unroll
            for (int r = 0; r < 4; ++r) {
                int lr  = m0 + wm * 64 + i * 16 + lg * 4 + r;
                int col = n0 + wn * (BN / 2) + j * 16 + l15;
                float c = acc[i][j][r];
                if (EPI == 1) {
                    if (lr < cnt)
                        outH[(size_t)(off + lr) * N + col] = (f16_t)fmaxf(c + bias[(size_t)e * N + col], 0.f);
                } else if (EPI == 2) {
                    if (lr < cnt) {
                        int token = idxg[off + lr];
                        int slot = (top[token].x == e) ? 0 : 1;
                        float w = comb[token * 8 + e];
                        eogW[((size_t)token * 2 + slot) * N + col] = (f16_t)(w * (c + bias[(size_t)e * N + col]));
                    }
                } else {
                    if (col < NCLIP)
                        outF[(size_t)lr * NCLIP + col] = c + bias[col];
                }
            }
        }
    }
}

// -----------------------------------------------------------------------------
extern "C" void kernel_launch(void* const* d_in, const int* in_sizes, int n_in,
                              void* d_out, int out_size, void* d_ws, size_t ws_size,
                              hipStream_t stream)
{
    const float* x   = (const float*)d_in[0];
    const float* w1  = (const float*)d_in[1];
    const float* b1  = (const float*)d_in[2];
    const float* w2  = (const float*)d_in[3];
    const float* b2  = (const float*)d_in[4];
    const float* pw  = (const float*)d_in[5];
    const float* pb  = (const float*)d_in[6];
    const float* rw  = (const float*)d_in[7];
    const float* rb  = (const float*)d_in[8];
    const float* ew1 = (const float*)d_in[9];
    const float* eb1 = (const float*)d_in[10];
    const float* ew2 = (const float*)d_in[11];
    const float* eb2 = (const float*)d_in[12];
    const float* cw  = (const float*)d_in[13];
    const float* cb  = (const float*)d_in[14];
    float* out = (float*)d_out;

    char* ws = (char*)d_ws;
    bf16_t* wsw  = (bf16_t*)(ws + 0);            //  320 KB
    float*  hbar = (float*)(ws + 327680);        //    1 MB
    float*  h    = (float*)(ws + 1376256);       //    8 MB (f32) — later reused as eog
    f16_t*  eog  = (f16_t*)(ws + 1376256);       //    8 MB f16 [token][slot][D] (aliases h)
    float*  comb = (float*)(ws + 9764864);       //   64 KB
    int2*   top  = (int2*)(ws + 9830400);        //   16 KB
    int*    meta = (int*)(ws + 9846784);         //   64 B
    int*    idxg = (int*)(ws + 9847040);         //   16 KB
    f16_t*  hidg = (f16_t*)(ws + 9863424);       // 16.5 MB -> ends 27164928
    f16_t*  ew1h = (f16_t*)(ws + 27164928);      //   24 MB
    f16_t*  ew2h = (f16_t*)(ws + 52330752);      //   24 MB
    f16_t*  clsh = (f16_t*)(ws + 77496576);      //    2 MB -> 79593728

    const bool f16w = ws_size >= 79593728ull;

    k_prep_w2<<<320, 256, 0, stream>>>(w2, wsw);
    if (f16w)
        k_prep_exp<<<25576, 256, 0, stream>>>(ew1, ew2, cw, ew1h, ew2h, clsh);
    k_conv<<<2048, 256, 0, stream>>>(x, w1, b1, wsw, b2, hbar);
    k_proj<<<dim3(32, 16), 256, 0, stream>>>(hbar, pw, pb, h);
    k_router<<<512, 256, 0, stream>>>(h, rw, rb, comb, top);
    k_index<<<1, 256, 0, stream>>>(top, meta, idxg);
    k_moe<1, 4><<<dim3(16, 16, 6), 256, 0, stream>>>(
        h, nullptr, nullptr, ew1, f16w ? ew1h : nullptr, eb1,
        hidg, nullptr, nullptr, comb, top, meta, idxg, HH, DD, HH);
    k_moe<2, 4><<<dim3(16, 8, 6), 256, 0, stream>>>(
        nullptr, hidg, nullptr, ew2, f16w ? ew2h : nullptr, eb2,
        nullptr, eog, nullptr, comb, top, meta, idxg, DD, HH, DD);
    k_moe<3, 2><<<dim3(16, 16, 1), 256, 0, stream>>>(
        nullptr, nullptr, eog, cw, f16w ? clsh : nullptr, cb,
        nullptr, nullptr, out, comb, top, meta, idxg, DD, DD, NC);
}